// Round 6
// baseline (4730.161 us; speedup 1.0000x reference)
//
#include <hip/hip_runtime.h>

#define E_EDGES 100000
#define E_PAD   100096   // 782 * 128
#define NNODES  10000
#define NPAD    10112    // 79 * 128
#define NGRAPHS 64

typedef __attribute__((ext_vector_type(4))) float f32x4;
typedef __attribute__((ext_vector_type(8))) short short8;

__device__ __forceinline__ unsigned short f2bf(float f) {
  union { float f; unsigned u; } v; v.f = f;
  unsigned u = v.u;
  return (unsigned short)((u + 0x7FFFu + ((u >> 16) & 1u)) >> 16);
}
__device__ __forceinline__ float bf2f(unsigned short h) {
  union { unsigned u; float f; } v; v.u = ((unsigned)h) << 16;
  return v.f;
}

// ---------------- tiled transpose + bf16 convert (coalesced both sides)
struct TDesc { const float* src; unsigned short* dst; int R, C, srcLd, dstLd; };
struct TDescs { TDesc d[10]; };

__global__ __launch_bounds__(256) void transpose_all(TDescs ds) {
  TDesc t = ds.d[blockIdx.z];
  int x0 = blockIdx.x * 32, y0 = blockIdx.y * 32;
  if (x0 >= t.C || y0 >= t.R) return;
  __shared__ float tile[32][33];
  int tx = threadIdx.x & 31, ty = threadIdx.x >> 5;   // ty 0..7
#pragma unroll
  for (int i = 0; i < 4; ++i)
    tile[ty + i * 8][tx] = t.src[(size_t)(y0 + ty + i * 8) * t.srcLd + x0 + tx];
  __syncthreads();
#pragma unroll
  for (int i = 0; i < 4; ++i) {
    int c = ty + i * 8;
    t.dst[(size_t)(x0 + c) * t.dstLd + y0 + tx] = f2bf(tile[tx][c]);
  }
}

// ---------------- M_t[2048][64]: rows k<50 = rbf_W @ Win_rbf; row 50 = rbf_b@Win_rbf + bin; rest 0
__global__ void mbuild_kernel(const float* __restrict__ rbf_W, const float* __restrict__ rbf_b,
                              const float* __restrict__ e_Win, const float* __restrict__ e_bin,
                              const float* __restrict__ f_Win, const float* __restrict__ f_bin,
                              unsigned short* __restrict__ M_t) {
  int gid = blockIdx.x * 256 + threadIdx.x;   // 2048*64
  int n = gid >> 6, k = gid & 63;
  const float* Wp; float bn; int col;
  if (n < 1024) { Wp = e_Win + 1024 * 1024; col = n;        bn = e_bin[n]; }
  else          { Wp = f_Win + 1024 * 1024; col = n - 1024; bn = f_bin[n - 1024]; }
  float acc = 0.f;
  if (k < 50) {
    for (int i = 0; i < 512; ++i) acc += rbf_W[k * 512 + i] * Wp[(size_t)i * 1024 + col];
  } else if (k == 50) {
    for (int i = 0; i < 512; ++i) acc += rbf_b[i] * Wp[(size_t)i * 1024 + col];
    acc += bn;
  }
  M_t[n * 64 + k] = f2bf(acc);
}

// ---------------- G[E_PAD][64]: gauss(dist) cols 0..49, col 50 = 1 (bias lane), rest 0
__global__ void gauss_kernel(const float* __restrict__ dist, unsigned short* __restrict__ G) {
  int gid = blockIdx.x * 256 + threadIdx.x;
  if (gid >= E_PAD * 64) return;
  int e = gid >> 6, g = gid & 63;
  float val = 0.f;
  if (e < E_EDGES) {
    if (g < 50) {
      const float step = 12.0f / 49.0f;
      float d = dist[e] - step * (float)g;
      val = __expf((-0.5f / (step * step)) * d * d);
    } else if (g == 50) val = 1.0f;
  }
  G[gid] = f2bf(val);
}

// ---------------- x f32 -> xb bf16 (rows >= NNODES zeroed)
__global__ void xconv_kernel(const float* __restrict__ x, unsigned short* __restrict__ xb) {
  int gid = blockIdx.x * 256 + threadIdx.x;   // NPAD*512
  int r = gid >> 9;
  xb[gid] = f2bf(r < NNODES ? x[gid] : 0.f);
}

// ---------------- GEMM (1D grid, col-fastest + XCD-chunked swizzle).
// MODE: 0 = plain C=A@Bt^T; 1 = C = res + silu(..+bias); 2 = fused row-dot -> atomicAdd(pairs).
template<int MODE>
__global__ __launch_bounds__(256, 4)
void gemm_kernel(const unsigned short* __restrict__ A, const unsigned short* __restrict__ Bt,
                 const float* __restrict__ bias, unsigned short* __restrict__ C,
                 const float* __restrict__ wout, float* __restrict__ pairs,
                 int K, int ldc, int nRows, int nColBlk) {
  __shared__ __align__(16) unsigned short As[128 * 64];
  __shared__ __align__(16) unsigned short Bs[128 * 64];
  // bijective XCD chunking (nblk % 8 == 0 guaranteed) + col-fastest within chunk
  const int nblk = gridDim.x;
  const int bid  = blockIdx.x;
  const int swz  = (bid & 7) * (nblk >> 3) + (bid >> 3);
  const int rowBlk = swz / nColBlk;
  const int colBlk = swz - rowBlk * nColBlk;
  const int rowBase = rowBlk * 128;
  const int colBase = colBlk * 128;
  const int tid  = threadIdx.x;
  const int wave = tid >> 6, lane = tid & 63;
  const int wr = wave >> 1, wc = wave & 1;
  const int lrow = lane & 15;
  const int lk   = (lane >> 4) << 3;
  const int r0 = (lane >> 4) << 2;
  const int c0 = lane & 15;
  const int ktRes = (colBase >> 6) + wc;   // used when MODE>=1 (K=1024)

  f32x4 acc[4][4];
#pragma unroll
  for (int m = 0; m < 4; ++m)
#pragma unroll
    for (int n = 0; n < 4; ++n) acc[m][n] = (f32x4){0.f, 0.f, 0.f, 0.f};

  unsigned short resv[4][4][4];

  const int nk = K >> 6;
  for (int kt = 0; kt < nk; ++kt) {
    const int k0 = kt << 6;
    __syncthreads();
#pragma unroll
    for (int i = 0; i < 4; ++i) {
      int chunk = wave * 4 + i;
      int eoff  = (chunk * 64 + lane) * 8;
      int r = eoff >> 6, c = eoff & 63;
      const unsigned short* ga = A  + (size_t)(rowBase + r) * K + (k0 + c);
      const unsigned short* gb = Bt + (size_t)(colBase + r) * K + (k0 + c);
      __builtin_amdgcn_global_load_lds((const __attribute__((address_space(1))) void*)ga,
          (__attribute__((address_space(3))) void*)(As + chunk * 512), 16, 0, 0);
      __builtin_amdgcn_global_load_lds((const __attribute__((address_space(1))) void*)gb,
          (__attribute__((address_space(3))) void*)(Bs + chunk * 512), 16, 0, 0);
    }
    __syncthreads();
#pragma unroll
    for (int kk = 0; kk < 2; ++kk) {
      short8 a[4], b[4];
#pragma unroll
      for (int m = 0; m < 4; ++m)
        a[m] = *(const short8*)&As[(wr * 64 + m * 16 + lrow) * 64 + kk * 32 + lk];
#pragma unroll
      for (int n = 0; n < 4; ++n)
        b[n] = *(const short8*)&Bs[(wc * 64 + n * 16 + lrow) * 64 + kk * 32 + lk];
#pragma unroll
      for (int m = 0; m < 4; ++m)
#pragma unroll
        for (int n = 0; n < 4; ++n)
          acc[m][n] = __builtin_amdgcn_mfma_f32_16x16x32_bf16(a[m], b[n], acc[m][n], 0, 0, 0);
    }
    if (MODE >= 1 && kt == ktRes) {
#pragma unroll
      for (int m = 0; m < 4; ++m)
#pragma unroll
        for (int n = 0; n < 4; ++n)
#pragma unroll
          for (int j = 0; j < 4; ++j)
            resv[m][n][j] = As[(wr * 64 + m * 16 + r0 + j) * 64 + (n * 16 + c0)];
    }
  }

  float rsum[4][4];
  if (MODE == 2) {
#pragma unroll
    for (int m = 0; m < 4; ++m)
#pragma unroll
      for (int j = 0; j < 4; ++j) rsum[m][j] = 0.f;
  }

#pragma unroll
  for (int n = 0; n < 4; ++n) {
    int colg = colBase + wc * 64 + n * 16 + c0;
    float bv = (MODE >= 1) ? bias[colg] : 0.f;
    float wv = (MODE == 2) ? wout[colg] : 0.f;
#pragma unroll
    for (int m = 0; m < 4; ++m) {
      int rowg = rowBase + wr * 64 + m * 16 + r0;
#pragma unroll
      for (int j = 0; j < 4; ++j) {
        float v = acc[m][n][j] + bv;
        float s;
        if (MODE >= 1) s = v / (1.f + __expf(-v)) + bf2f(resv[m][n][j]);
        else           s = v;
        if (MODE == 2) rsum[m][j] += s * wv;
        else           C[(size_t)(rowg + j) * ldc + colg] = f2bf(s);
      }
    }
  }

  if (MODE == 2) {
#pragma unroll
    for (int m = 0; m < 4; ++m)
#pragma unroll
      for (int j = 0; j < 4; ++j) {
        float v = rsum[m][j];
        v += __shfl_xor(v, 1); v += __shfl_xor(v, 2);
        v += __shfl_xor(v, 4); v += __shfl_xor(v, 8);
        if (c0 == 0) {
          int rowg = rowBase + wr * 64 + m * 16 + r0 + j;
          if (rowg < nRows) atomicAdd(&pairs[rowg], v);
        }
      }
  }
}

// ---------------- fused layer-1 (chunk rows [e0, e0+rowsPad)):
// H[r] = silu(G[e0+r] @ M_t^T + PS[src][..] + PS[dst][..])
__global__ __launch_bounds__(256, 4)
void fuse1_kernel(const unsigned short* __restrict__ G, const unsigned short* __restrict__ M_t,
                  const unsigned short* __restrict__ PS, const int* __restrict__ srcI,
                  const int* __restrict__ dstI, unsigned short* __restrict__ H,
                  int colOff, int e0) {
  __shared__ __align__(16) unsigned short Gs[128 * 64];
  __shared__ __align__(16) unsigned short Ms[128 * 64];
  __shared__ int sIdx[128], dIdx[128];
  const int rowBase = blockIdx.x * 128;       // chunk-local
  const int nBase   = blockIdx.y * 128;       // within [0,1024)
  const int tid  = threadIdx.x;
  const int wave = tid >> 6, lane = tid & 63;
  const int wr = wave >> 1, wc = wave & 1;
  const int lrow = lane & 15;
  const int lk   = (lane >> 4) << 3;

  {
    int r = tid & 127;
    int e = e0 + rowBase + r;
    if (tid < 128) sIdx[r] = (e < E_EDGES) ? srcI[e] : 0;
    else           dIdx[r] = (e < E_EDGES) ? dstI[e] : 0;
  }
#pragma unroll
  for (int i = 0; i < 4; ++i) {
    int chunk = wave * 4 + i;
    int eoff  = (chunk * 64 + lane) * 8;
    const unsigned short* gg = G   + (size_t)(e0 + rowBase) * 64 + eoff;
    const unsigned short* gm = M_t + (size_t)(colOff + nBase) * 64 + eoff;
    __builtin_amdgcn_global_load_lds((const __attribute__((address_space(1))) void*)gg,
        (__attribute__((address_space(3))) void*)(Gs + chunk * 512), 16, 0, 0);
    __builtin_amdgcn_global_load_lds((const __attribute__((address_space(1))) void*)gm,
        (__attribute__((address_space(3))) void*)(Ms + chunk * 512), 16, 0, 0);
  }
  __syncthreads();

  f32x4 acc[4][4];
#pragma unroll
  for (int m = 0; m < 4; ++m)
#pragma unroll
    for (int n = 0; n < 4; ++n) acc[m][n] = (f32x4){0.f, 0.f, 0.f, 0.f};
#pragma unroll
  for (int kk = 0; kk < 2; ++kk) {
    short8 a[4], b[4];
#pragma unroll
    for (int m = 0; m < 4; ++m)
      a[m] = *(const short8*)&Gs[(wr * 64 + m * 16 + lrow) * 64 + kk * 32 + lk];
#pragma unroll
    for (int n = 0; n < 4; ++n)
      b[n] = *(const short8*)&Ms[(wc * 64 + n * 16 + lrow) * 64 + kk * 32 + lk];
#pragma unroll
    for (int m = 0; m < 4; ++m)
#pragma unroll
      for (int n = 0; n < 4; ++n)
        acc[m][n] = __builtin_amdgcn_mfma_f32_16x16x32_bf16(a[m], b[n], acc[m][n], 0, 0, 0);
  }

  const int r0 = (lane >> 4) << 2;
  const int c0 = lane & 15;
#pragma unroll
  for (int m = 0; m < 4; ++m)
#pragma unroll
    for (int j = 0; j < 4; ++j) {
      int rowl = wr * 64 + m * 16 + r0 + j;
      int s = sIdx[rowl], d = dIdx[rowl];
      const unsigned short* prs = PS + (size_t)s * 4096 + 2 * colOff;
      const unsigned short* prd = PS + (size_t)d * 4096 + 2 * colOff + 1024;
#pragma unroll
      for (int n = 0; n < 4; ++n) {
        int nloc = nBase + wc * 64 + n * 16 + c0;
        float v = acc[m][n][j] + bf2f(prs[nloc]) + bf2f(prd[nloc]);
        H[(size_t)(rowBase + rowl) * 1024 + nloc] = f2bf(v / (1.f + __expf(-v)));
      }
    }
}

// ---------------- init: pairs = bout, d_out = 0
__global__ void init_kernel(float* __restrict__ pe, float* __restrict__ pf,
                            float* __restrict__ out, int outN,
                            const float* __restrict__ eb, const float* __restrict__ fb) {
  int i = blockIdx.x * 256 + threadIdx.x;
  if (i < E_EDGES) pe[i] = eb[0];
  else if (i < 2 * E_EDGES) pf[i - E_EDGES] = fb[0];
  else if (i < 2 * E_EDGES + outN) out[i - 2 * E_EDGES] = 0.f;
}

__global__ void energy_kernel(const float* __restrict__ pairs, const int* __restrict__ srcI,
                              const int* __restrict__ batch, float* __restrict__ out) {
  __shared__ float bins[NGRAPHS];
  if (threadIdx.x < NGRAPHS) bins[threadIdx.x] = 0.f;
  __syncthreads();
  for (int e = blockIdx.x * 256 + threadIdx.x; e < E_EDGES; e += gridDim.x * 256)
    atomicAdd(&bins[batch[srcI[e]]], pairs[e]);
  __syncthreads();
  if (threadIdx.x < NGRAPHS)
    atomicAdd(&out[threadIdx.x], bins[threadIdx.x] * (1.0f / 1920.0f));
}

__global__ void force_kernel(const float* __restrict__ pairs, const int* __restrict__ srcI,
                             const float* __restrict__ vec, float* __restrict__ out) {
  int e = blockIdx.x * 256 + threadIdx.x;
  if (e >= E_EDGES) return;
  float p = pairs[e] * (1.0f / 32.0f);
  int s = srcI[e];
  atomicAdd(&out[64 + s * 3 + 0], p * vec[e * 3 + 0]);
  atomicAdd(&out[64 + s * 3 + 1], p * vec[e * 3 + 1]);
  atomicAdd(&out[64 + s * 3 + 2], p * vec[e * 3 + 2]);
}

extern "C" void kernel_launch(void* const* d_in, const int* in_sizes, int n_in,
                              void* d_out, int out_size, void* d_ws, size_t ws_size,
                              hipStream_t stream) {
  const float* x       = (const float*)d_in[0];
  const int*   ei      = (const int*)  d_in[1];
  const int*   batch   = (const int*)  d_in[2];
  const float* dist    = (const float*)d_in[3];
  const float* vec_hat = (const float*)d_in[4];
  const float* rbf_W   = (const float*)d_in[5];
  const float* rbf_b   = (const float*)d_in[6];
  const float* e_Win   = (const float*)d_in[7];
  const float* e_bin   = (const float*)d_in[8];
  const float* e_Wh    = (const float*)d_in[9];
  const float* e_bh    = (const float*)d_in[10];
  const float* e_Wout  = (const float*)d_in[11];
  const float* e_bout  = (const float*)d_in[12];
  const float* f_Win   = (const float*)d_in[13];
  const float* f_bin   = (const float*)d_in[14];
  const float* f_Wh    = (const float*)d_in[15];
  const float* f_bh    = (const float*)d_in[16];
  const float* f_Wout  = (const float*)d_in[17];
  const float* f_bout  = (const float*)d_in[18];

  const int* srcI = ei;
  const int* dstI = ei + E_EDGES;

  // ---- workspace layout (fixed part ~123.8 MB; activations chunked) ----
  size_t off = 0;
  char* base = (char*)d_ws;
  auto alloc = [&](size_t bytes) -> void* {
    void* p = base + off;
    off = (off + bytes + 255) & ~(size_t)255;
    return p;
  };
  unsigned short* WtN   = (unsigned short*)alloc((size_t)4096 * 512 * 2);
  unsigned short* Wt_eh = (unsigned short*)alloc((size_t)3 * 1024 * 1024 * 2);
  unsigned short* Wt_fh = (unsigned short*)alloc((size_t)3 * 1024 * 1024 * 2);
  unsigned short* M_t   = (unsigned short*)alloc((size_t)2048 * 64 * 2);
  unsigned short* xb    = (unsigned short*)alloc((size_t)NPAD * 512 * 2);
  unsigned short* G     = (unsigned short*)alloc((size_t)E_PAD * 64 * 2);
  unsigned short* PS    = (unsigned short*)alloc((size_t)NPAD * 4096 * 2);
  float* pairs_e = (float*)alloc((size_t)E_EDGES * 4);
  float* pairs_f = (float*)alloc((size_t)E_EDGES * 4);

  // chunk rows EC (multiple of 128): bufA+bufC cost 4096 B per row
  size_t avail = (ws_size > off + 4096) ? (ws_size - off - 4096) : 0;
  long long rows = (long long)(avail / 4096);
  int EC = (int)(rows - rows % 128);
  if (EC > E_PAD) EC = E_PAD;
  if (EC < 128) return;   // tripwire: clean failure, not a fault

  unsigned short* bufA = (unsigned short*)alloc((size_t)EC * 1024 * 2);
  unsigned short* bufC = (unsigned short*)alloc((size_t)EC * 1024 * 2);
  if (ws_size < off) return;  // tripwire

  // ---- init pairs + out
  init_kernel<<<(2 * E_EDGES + out_size + 255) / 256, 256, 0, stream>>>(
      pairs_e, pairs_f, (float*)d_out, out_size, e_bout, f_bout);

  // ---- weight transposes (one launch)
  TDescs td;
  td.d[0] = {e_Win,              WtN,               512, 1024, 1024, 512};
  td.d[1] = {e_Win + 512 * 1024, WtN + 1024 * 512,  512, 1024, 1024, 512};
  td.d[2] = {f_Win,              WtN + 2048 * 512,  512, 1024, 1024, 512};
  td.d[3] = {f_Win + 512 * 1024, WtN + 3072 * 512,  512, 1024, 1024, 512};
  for (int l = 0; l < 3; ++l) {
    td.d[4 + l] = {e_Wh + (size_t)l * 1048576, Wt_eh + (size_t)l * 1048576, 1024, 1024, 1024, 1024};
    td.d[7 + l] = {f_Wh + (size_t)l * 1048576, Wt_fh + (size_t)l * 1048576, 1024, 1024, 1024, 1024};
  }
  transpose_all<<<dim3(32, 32, 10), 256, 0, stream>>>(td);

  mbuild_kernel<<<(2048 * 64) / 256, 256, 0, stream>>>(rbf_W, rbf_b, e_Win, e_bin, f_Win, f_bin, M_t);
  gauss_kernel<<<(E_PAD * 64) / 256, 256, 0, stream>>>(dist, G);
  xconv_kernel<<<(NPAD * 512) / 256, 256, 0, stream>>>(x, xb);

  // ---- node-level projection: PS = xb @ WtN^T   [NPAD][4096]
  gemm_kernel<0><<<(NPAD / 128) * 32, 256, 0, stream>>>(
      xb, WtN, nullptr, PS, nullptr, nullptr, 512, 4096, NPAD, 32);

  // ---- chunked edge pipeline
  for (int e0 = 0; e0 < E_EDGES; e0 += EC) {
    int rem = E_EDGES - e0; if (rem > EC) rem = EC;
    int rowsPad = ((rem + 127) / 128) * 128;     // <= EC
    int nblk = (rowsPad / 128) * 8;
    dim3 gf(rowsPad / 128, 8);

    // energy chain
    fuse1_kernel<<<gf, 256, 0, stream>>>(G, M_t, PS, srcI, dstI, bufA, 0, e0);
    gemm_kernel<1><<<nblk, 256, 0, stream>>>(bufA, Wt_eh + (size_t)0 * 1048576, e_bh + 0,
                                             bufC, nullptr, nullptr, 1024, 1024, rowsPad, 8);
    gemm_kernel<1><<<nblk, 256, 0, stream>>>(bufC, Wt_eh + (size_t)1 * 1048576, e_bh + 1024,
                                             bufA, nullptr, nullptr, 1024, 1024, rowsPad, 8);
    gemm_kernel<2><<<nblk, 256, 0, stream>>>(bufA, Wt_eh + (size_t)2 * 1048576, e_bh + 2048,
                                             nullptr, e_Wout, pairs_e + e0, 1024, 1024, rem, 8);

    // force chain
    fuse1_kernel<<<gf, 256, 0, stream>>>(G, M_t, PS, srcI, dstI, bufC, 1024, e0);
    gemm_kernel<1><<<nblk, 256, 0, stream>>>(bufC, Wt_fh + (size_t)0 * 1048576, f_bh + 0,
                                             bufA, nullptr, nullptr, 1024, 1024, rowsPad, 8);
    gemm_kernel<1><<<nblk, 256, 0, stream>>>(bufA, Wt_fh + (size_t)1 * 1048576, f_bh + 1024,
                                             bufC, nullptr, nullptr, 1024, 1024, rowsPad, 8);
    gemm_kernel<2><<<nblk, 256, 0, stream>>>(bufC, Wt_fh + (size_t)2 * 1048576, f_bh + 2048,
                                             nullptr, f_Wout, pairs_f + e0, 1024, 1024, rem, 8);
  }

  // ---- reductions
  energy_kernel<<<256, 256, 0, stream>>>(pairs_e, srcI, batch, (float*)d_out);
  force_kernel<<<(E_EDGES + 255) / 256, 256, 0, stream>>>(pairs_f, srcI, vec_hat, (float*)d_out);
}

// Round 7
// 2224.168 us; speedup vs baseline: 2.1267x; 2.1267x over previous
//
#include <hip/hip_runtime.h>

#define E_EDGES 100000
#define E_PAD   100096   // 782 * 128
#define NNODES  10000
#define NPAD    10112    // 79 * 128
#define NGRAPHS 64

typedef __attribute__((ext_vector_type(4))) float f32x4;
typedef __attribute__((ext_vector_type(8))) short short8;

__device__ __forceinline__ unsigned short f2bf(float f) {
  union { float f; unsigned u; } v; v.f = f;
  unsigned u = v.u;
  return (unsigned short)((u + 0x7FFFu + ((u >> 16) & 1u)) >> 16);
}
__device__ __forceinline__ float bf2f(unsigned short h) {
  union { unsigned u; float f; } v; v.u = ((unsigned)h) << 16;
  return v.f;
}

// ---------------- tiled transpose + bf16 convert (coalesced both sides)
struct TDesc { const float* src; unsigned short* dst; int R, C, srcLd, dstLd; };
struct TDescs { TDesc d[10]; };

__global__ __launch_bounds__(256) void transpose_all(TDescs ds) {
  TDesc t = ds.d[blockIdx.z];
  int x0 = blockIdx.x * 32, y0 = blockIdx.y * 32;
  if (x0 >= t.C || y0 >= t.R) return;
  __shared__ float tile[32][33];
  int tx = threadIdx.x & 31, ty = threadIdx.x >> 5;   // ty 0..7
#pragma unroll
  for (int i = 0; i < 4; ++i)
    tile[ty + i * 8][tx] = t.src[(size_t)(y0 + ty + i * 8) * t.srcLd + x0 + tx];
  __syncthreads();
#pragma unroll
  for (int i = 0; i < 4; ++i) {
    int c = ty + i * 8;
    t.dst[(size_t)(x0 + c) * t.dstLd + y0 + tx] = f2bf(tile[tx][c]);
  }
}

// ---------------- M_t[2048][64]: rows k<50 = rbf_W @ Win_rbf; row 50 = rbf_b@Win_rbf + bin; rest 0
__global__ void mbuild_kernel(const float* __restrict__ rbf_W, const float* __restrict__ rbf_b,
                              const float* __restrict__ e_Win, const float* __restrict__ e_bin,
                              const float* __restrict__ f_Win, const float* __restrict__ f_bin,
                              unsigned short* __restrict__ M_t) {
  int gid = blockIdx.x * 256 + threadIdx.x;   // 2048*64
  int n = gid >> 6, k = gid & 63;
  const float* Wp; float bn; int col;
  if (n < 1024) { Wp = e_Win + 1024 * 1024; col = n;        bn = e_bin[n]; }
  else          { Wp = f_Win + 1024 * 1024; col = n - 1024; bn = f_bin[n - 1024]; }
  float acc = 0.f;
  if (k < 50) {
    for (int i = 0; i < 512; ++i) acc += rbf_W[k * 512 + i] * Wp[(size_t)i * 1024 + col];
  } else if (k == 50) {
    for (int i = 0; i < 512; ++i) acc += rbf_b[i] * Wp[(size_t)i * 1024 + col];
    acc += bn;
  }
  M_t[n * 64 + k] = f2bf(acc);
}

// ---------------- G[E_PAD][64]: gauss(dist) cols 0..49, col 50 = 1 (bias lane), rest 0
__global__ void gauss_kernel(const float* __restrict__ dist, unsigned short* __restrict__ G) {
  int gid = blockIdx.x * 256 + threadIdx.x;
  if (gid >= E_PAD * 64) return;
  int e = gid >> 6, g = gid & 63;
  float val = 0.f;
  if (e < E_EDGES) {
    if (g < 50) {
      const float step = 12.0f / 49.0f;
      float d = dist[e] - step * (float)g;
      val = __expf((-0.5f / (step * step)) * d * d);
    } else if (g == 50) val = 1.0f;
  }
  G[gid] = f2bf(val);
}

// ---------------- x f32 -> xb bf16 (rows >= NNODES zeroed)
__global__ void xconv_kernel(const float* __restrict__ x, unsigned short* __restrict__ xb) {
  int gid = blockIdx.x * 256 + threadIdx.x;   // NPAD*512
  int r = gid >> 9;
  xb[gid] = f2bf(r < NNODES ? x[gid] : 0.f);
}

// ---------------- GEMM (1D grid, col-fastest + XCD-chunked swizzle).
// MODE: 0 = plain C=A@Bt^T; 1 = C = res + silu(..+bias); 2 = fused row-dot -> atomicAdd(pairs).
// launch_bounds (256,3): VGPR cap ~170 (acc needs 64; round-6's (256,4) cap=64 SPILLED to scratch:
// WRITE_SIZE 8.8MB -> 659MB, dur 160 -> 280us. Do not raise min-waves above 3.)
template<int MODE>
__global__ __launch_bounds__(256, 3)
void gemm_kernel(const unsigned short* __restrict__ A, const unsigned short* __restrict__ Bt,
                 const float* __restrict__ bias, unsigned short* __restrict__ C,
                 const float* __restrict__ wout, float* __restrict__ pairs,
                 int K, int ldc, int nRows, int nColBlk) {
  __shared__ __align__(16) unsigned short As[128 * 64];
  __shared__ __align__(16) unsigned short Bs[128 * 64];
  // bijective XCD chunking (nblk % 8 == 0 guaranteed) + col-fastest within chunk
  const int nblk = gridDim.x;
  const int bid  = blockIdx.x;
  const int swz  = (bid & 7) * (nblk >> 3) + (bid >> 3);
  const int rowBlk = swz / nColBlk;
  const int colBlk = swz - rowBlk * nColBlk;
  const int rowBase = rowBlk * 128;
  const int colBase = colBlk * 128;
  const int tid  = threadIdx.x;
  const int wave = tid >> 6, lane = tid & 63;
  const int wr = wave >> 1, wc = wave & 1;
  const int lrow = lane & 15;
  const int lk   = (lane >> 4) << 3;
  const int r0 = (lane >> 4) << 2;
  const int c0 = lane & 15;
  const int ktRes = (colBase >> 6) + wc;   // used when MODE>=1 (K=1024)

  f32x4 acc[4][4];
#pragma unroll
  for (int m = 0; m < 4; ++m)
#pragma unroll
    for (int n = 0; n < 4; ++n) acc[m][n] = (f32x4){0.f, 0.f, 0.f, 0.f};

  unsigned short resv[4][4][4];

  const int nk = K >> 6;
  for (int kt = 0; kt < nk; ++kt) {
    const int k0 = kt << 6;
    __syncthreads();
#pragma unroll
    for (int i = 0; i < 4; ++i) {
      int chunk = wave * 4 + i;
      int eoff  = (chunk * 64 + lane) * 8;
      int r = eoff >> 6, c = eoff & 63;
      const unsigned short* ga = A  + (size_t)(rowBase + r) * K + (k0 + c);
      const unsigned short* gb = Bt + (size_t)(colBase + r) * K + (k0 + c);
      __builtin_amdgcn_global_load_lds((const __attribute__((address_space(1))) void*)ga,
          (__attribute__((address_space(3))) void*)(As + chunk * 512), 16, 0, 0);
      __builtin_amdgcn_global_load_lds((const __attribute__((address_space(1))) void*)gb,
          (__attribute__((address_space(3))) void*)(Bs + chunk * 512), 16, 0, 0);
    }
    __syncthreads();
#pragma unroll
    for (int kk = 0; kk < 2; ++kk) {
      short8 a[4], b[4];
#pragma unroll
      for (int m = 0; m < 4; ++m)
        a[m] = *(const short8*)&As[(wr * 64 + m * 16 + lrow) * 64 + kk * 32 + lk];
#pragma unroll
      for (int n = 0; n < 4; ++n)
        b[n] = *(const short8*)&Bs[(wc * 64 + n * 16 + lrow) * 64 + kk * 32 + lk];
#pragma unroll
      for (int m = 0; m < 4; ++m)
#pragma unroll
        for (int n = 0; n < 4; ++n)
          acc[m][n] = __builtin_amdgcn_mfma_f32_16x16x32_bf16(a[m], b[n], acc[m][n], 0, 0, 0);
    }
    if (MODE >= 1 && kt == ktRes) {
#pragma unroll
      for (int m = 0; m < 4; ++m)
#pragma unroll
        for (int n = 0; n < 4; ++n)
#pragma unroll
          for (int j = 0; j < 4; ++j)
            resv[m][n][j] = As[(wr * 64 + m * 16 + r0 + j) * 64 + (n * 16 + c0)];
    }
  }

  float rsum[4][4];
  if (MODE == 2) {
#pragma unroll
    for (int m = 0; m < 4; ++m)
#pragma unroll
      for (int j = 0; j < 4; ++j) rsum[m][j] = 0.f;
  }

#pragma unroll
  for (int n = 0; n < 4; ++n) {
    int colg = colBase + wc * 64 + n * 16 + c0;
    float bv = (MODE >= 1) ? bias[colg] : 0.f;
    float wv = (MODE == 2) ? wout[colg] : 0.f;
#pragma unroll
    for (int m = 0; m < 4; ++m) {
      int rowg = rowBase + wr * 64 + m * 16 + r0;
#pragma unroll
      for (int j = 0; j < 4; ++j) {
        float v = acc[m][n][j] + bv;
        float s;
        if (MODE >= 1) s = v / (1.f + __expf(-v)) + bf2f(resv[m][n][j]);
        else           s = v;
        if (MODE == 2) rsum[m][j] += s * wv;
        else           C[(size_t)(rowg + j) * ldc + colg] = f2bf(s);
      }
    }
  }

  if (MODE == 2) {
#pragma unroll
    for (int m = 0; m < 4; ++m)
#pragma unroll
      for (int j = 0; j < 4; ++j) {
        float v = rsum[m][j];
        v += __shfl_xor(v, 1); v += __shfl_xor(v, 2);
        v += __shfl_xor(v, 4); v += __shfl_xor(v, 8);
        if (c0 == 0) {
          int rowg = rowBase + wr * 64 + m * 16 + r0 + j;
          if (rowg < nRows) atomicAdd(&pairs[rowg], v);
        }
      }
  }
}

// ---------------- fused layer-1 (chunk rows [e0, e0+rowsPad)):
// H[r] = silu(G[e0+r] @ M_t^T + PS[src][..] + PS[dst][..])
__global__ __launch_bounds__(256, 3)
void fuse1_kernel(const unsigned short* __restrict__ G, const unsigned short* __restrict__ M_t,
                  const unsigned short* __restrict__ PS, const int* __restrict__ srcI,
                  const int* __restrict__ dstI, unsigned short* __restrict__ H,
                  int colOff, int e0) {
  __shared__ __align__(16) unsigned short Gs[128 * 64];
  __shared__ __align__(16) unsigned short Ms[128 * 64];
  __shared__ int sIdx[128], dIdx[128];
  const int rowBase = blockIdx.x * 128;       // chunk-local
  const int nBase   = blockIdx.y * 128;       // within [0,1024)
  const int tid  = threadIdx.x;
  const int wave = tid >> 6, lane = tid & 63;
  const int wr = wave >> 1, wc = wave & 1;
  const int lrow = lane & 15;
  const int lk   = (lane >> 4) << 3;

  {
    int r = tid & 127;
    int e = e0 + rowBase + r;
    if (tid < 128) sIdx[r] = (e < E_EDGES) ? srcI[e] : 0;
    else           dIdx[r] = (e < E_EDGES) ? dstI[e] : 0;
  }
#pragma unroll
  for (int i = 0; i < 4; ++i) {
    int chunk = wave * 4 + i;
    int eoff  = (chunk * 64 + lane) * 8;
    const unsigned short* gg = G   + (size_t)(e0 + rowBase) * 64 + eoff;
    const unsigned short* gm = M_t + (size_t)(colOff + nBase) * 64 + eoff;
    __builtin_amdgcn_global_load_lds((const __attribute__((address_space(1))) void*)gg,
        (__attribute__((address_space(3))) void*)(Gs + chunk * 512), 16, 0, 0);
    __builtin_amdgcn_global_load_lds((const __attribute__((address_space(1))) void*)gm,
        (__attribute__((address_space(3))) void*)(Ms + chunk * 512), 16, 0, 0);
  }
  __syncthreads();

  f32x4 acc[4][4];
#pragma unroll
  for (int m = 0; m < 4; ++m)
#pragma unroll
    for (int n = 0; n < 4; ++n) acc[m][n] = (f32x4){0.f, 0.f, 0.f, 0.f};
#pragma unroll
  for (int kk = 0; kk < 2; ++kk) {
    short8 a[4], b[4];
#pragma unroll
    for (int m = 0; m < 4; ++m)
      a[m] = *(const short8*)&Gs[(wr * 64 + m * 16 + lrow) * 64 + kk * 32 + lk];
#pragma unroll
    for (int n = 0; n < 4; ++n)
      b[n] = *(const short8*)&Ms[(wc * 64 + n * 16 + lrow) * 64 + kk * 32 + lk];
#pragma unroll
    for (int m = 0; m < 4; ++m)
#pragma unroll
      for (int n = 0; n < 4; ++n)
        acc[m][n] = __builtin_amdgcn_mfma_f32_16x16x32_bf16(a[m], b[n], acc[m][n], 0, 0, 0);
  }

  const int r0 = (lane >> 4) << 2;
  const int c0 = lane & 15;
#pragma unroll
  for (int m = 0; m < 4; ++m)
#pragma unroll
    for (int j = 0; j < 4; ++j) {
      int rowl = wr * 64 + m * 16 + r0 + j;
      int s = sIdx[rowl], d = dIdx[rowl];
      const unsigned short* prs = PS + (size_t)s * 4096 + 2 * colOff;
      const unsigned short* prd = PS + (size_t)d * 4096 + 2 * colOff + 1024;
#pragma unroll
      for (int n = 0; n < 4; ++n) {
        int nloc = nBase + wc * 64 + n * 16 + c0;
        float v = acc[m][n][j] + bf2f(prs[nloc]) + bf2f(prd[nloc]);
        H[(size_t)(rowBase + rowl) * 1024 + nloc] = f2bf(v / (1.f + __expf(-v)));
      }
    }
}

// ---------------- init: pairs = bout, d_out = 0
__global__ void init_kernel(float* __restrict__ pe, float* __restrict__ pf,
                            float* __restrict__ out, int outN,
                            const float* __restrict__ eb, const float* __restrict__ fb) {
  int i = blockIdx.x * 256 + threadIdx.x;
  if (i < E_EDGES) pe[i] = eb[0];
  else if (i < 2 * E_EDGES) pf[i - E_EDGES] = fb[0];
  else if (i < 2 * E_EDGES + outN) out[i - 2 * E_EDGES] = 0.f;
}

__global__ void energy_kernel(const float* __restrict__ pairs, const int* __restrict__ srcI,
                              const int* __restrict__ batch, float* __restrict__ out) {
  __shared__ float bins[NGRAPHS];
  if (threadIdx.x < NGRAPHS) bins[threadIdx.x] = 0.f;
  __syncthreads();
  for (int e = blockIdx.x * 256 + threadIdx.x; e < E_EDGES; e += gridDim.x * 256)
    atomicAdd(&bins[batch[srcI[e]]], pairs[e]);
  __syncthreads();
  if (threadIdx.x < NGRAPHS)
    atomicAdd(&out[threadIdx.x], bins[threadIdx.x] * (1.0f / 1920.0f));
}

__global__ void force_kernel(const float* __restrict__ pairs, const int* __restrict__ srcI,
                             const float* __restrict__ vec, float* __restrict__ out) {
  int e = blockIdx.x * 256 + threadIdx.x;
  if (e >= E_EDGES) return;
  float p = pairs[e] * (1.0f / 32.0f);
  int s = srcI[e];
  atomicAdd(&out[64 + s * 3 + 0], p * vec[e * 3 + 0]);
  atomicAdd(&out[64 + s * 3 + 1], p * vec[e * 3 + 1]);
  atomicAdd(&out[64 + s * 3 + 2], p * vec[e * 3 + 2]);
}

extern "C" void kernel_launch(void* const* d_in, const int* in_sizes, int n_in,
                              void* d_out, int out_size, void* d_ws, size_t ws_size,
                              hipStream_t stream) {
  const float* x       = (const float*)d_in[0];
  const int*   ei      = (const int*)  d_in[1];
  const int*   batch   = (const int*)  d_in[2];
  const float* dist    = (const float*)d_in[3];
  const float* vec_hat = (const float*)d_in[4];
  const float* rbf_W   = (const float*)d_in[5];
  const float* rbf_b   = (const float*)d_in[6];
  const float* e_Win   = (const float*)d_in[7];
  const float* e_bin   = (const float*)d_in[8];
  const float* e_Wh    = (const float*)d_in[9];
  const float* e_bh    = (const float*)d_in[10];
  const float* e_Wout  = (const float*)d_in[11];
  const float* e_bout  = (const float*)d_in[12];
  const float* f_Win   = (const float*)d_in[13];
  const float* f_bin   = (const float*)d_in[14];
  const float* f_Wh    = (const float*)d_in[15];
  const float* f_bh    = (const float*)d_in[16];
  const float* f_Wout  = (const float*)d_in[17];
  const float* f_bout  = (const float*)d_in[18];

  const int* srcI = ei;
  const int* dstI = ei + E_EDGES;

  // ---- workspace layout (fixed part ~123.8 MB; activations chunked) ----
  size_t off = 0;
  char* base = (char*)d_ws;
  auto alloc = [&](size_t bytes) -> void* {
    void* p = base + off;
    off = (off + bytes + 255) & ~(size_t)255;
    return p;
  };
  unsigned short* WtN   = (unsigned short*)alloc((size_t)4096 * 512 * 2);
  unsigned short* Wt_eh = (unsigned short*)alloc((size_t)3 * 1024 * 1024 * 2);
  unsigned short* Wt_fh = (unsigned short*)alloc((size_t)3 * 1024 * 1024 * 2);
  unsigned short* M_t   = (unsigned short*)alloc((size_t)2048 * 64 * 2);
  unsigned short* xb    = (unsigned short*)alloc((size_t)NPAD * 512 * 2);
  unsigned short* G     = (unsigned short*)alloc((size_t)E_PAD * 64 * 2);
  unsigned short* PS    = (unsigned short*)alloc((size_t)NPAD * 4096 * 2);
  float* pairs_e = (float*)alloc((size_t)E_EDGES * 4);
  float* pairs_f = (float*)alloc((size_t)E_EDGES * 4);

  // chunk rows EC (multiple of 128): bufA+bufC cost 4096 B per row
  size_t avail = (ws_size > off + 4096) ? (ws_size - off - 4096) : 0;
  long long rows = (long long)(avail / 4096);
  int EC = (int)(rows - rows % 128);
  if (EC > E_PAD) EC = E_PAD;
  if (EC < 128) return;   // tripwire: clean failure, not a fault

  unsigned short* bufA = (unsigned short*)alloc((size_t)EC * 1024 * 2);
  unsigned short* bufC = (unsigned short*)alloc((size_t)EC * 1024 * 2);
  if (ws_size < off) return;  // tripwire

  // ---- init pairs + out
  init_kernel<<<(2 * E_EDGES + out_size + 255) / 256, 256, 0, stream>>>(
      pairs_e, pairs_f, (float*)d_out, out_size, e_bout, f_bout);

  // ---- weight transposes (one launch)
  TDescs td;
  td.d[0] = {e_Win,              WtN,               512, 1024, 1024, 512};
  td.d[1] = {e_Win + 512 * 1024, WtN + 1024 * 512,  512, 1024, 1024, 512};
  td.d[2] = {f_Win,              WtN + 2048 * 512,  512, 1024, 1024, 512};
  td.d[3] = {f_Win + 512 * 1024, WtN + 3072 * 512,  512, 1024, 1024, 512};
  for (int l = 0; l < 3; ++l) {
    td.d[4 + l] = {e_Wh + (size_t)l * 1048576, Wt_eh + (size_t)l * 1048576, 1024, 1024, 1024, 1024};
    td.d[7 + l] = {f_Wh + (size_t)l * 1048576, Wt_fh + (size_t)l * 1048576, 1024, 1024, 1024, 1024};
  }
  transpose_all<<<dim3(32, 32, 10), 256, 0, stream>>>(td);

  mbuild_kernel<<<(2048 * 64) / 256, 256, 0, stream>>>(rbf_W, rbf_b, e_Win, e_bin, f_Win, f_bin, M_t);
  gauss_kernel<<<(E_PAD * 64) / 256, 256, 0, stream>>>(dist, G);
  xconv_kernel<<<(NPAD * 512) / 256, 256, 0, stream>>>(x, xb);

  // ---- node-level projection: PS = xb @ WtN^T   [NPAD][4096]
  gemm_kernel<0><<<(NPAD / 128) * 32, 256, 0, stream>>>(
      xb, WtN, nullptr, PS, nullptr, nullptr, 512, 4096, NPAD, 32);

  // ---- chunked edge pipeline
  for (int e0 = 0; e0 < E_EDGES; e0 += EC) {
    int rem = E_EDGES - e0; if (rem > EC) rem = EC;
    int rowsPad = ((rem + 127) / 128) * 128;     // <= EC
    int nblk = (rowsPad / 128) * 8;
    dim3 gf(rowsPad / 128, 8);

    // energy chain
    fuse1_kernel<<<gf, 256, 0, stream>>>(G, M_t, PS, srcI, dstI, bufA, 0, e0);
    gemm_kernel<1><<<nblk, 256, 0, stream>>>(bufA, Wt_eh + (size_t)0 * 1048576, e_bh + 0,
                                             bufC, nullptr, nullptr, 1024, 1024, rowsPad, 8);
    gemm_kernel<1><<<nblk, 256, 0, stream>>>(bufC, Wt_eh + (size_t)1 * 1048576, e_bh + 1024,
                                             bufA, nullptr, nullptr, 1024, 1024, rowsPad, 8);
    gemm_kernel<2><<<nblk, 256, 0, stream>>>(bufA, Wt_eh + (size_t)2 * 1048576, e_bh + 2048,
                                             nullptr, e_Wout, pairs_e + e0, 1024, 1024, rem, 8);

    // force chain
    fuse1_kernel<<<gf, 256, 0, stream>>>(G, M_t, PS, srcI, dstI, bufC, 1024, e0);
    gemm_kernel<1><<<nblk, 256, 0, stream>>>(bufC, Wt_fh + (size_t)0 * 1048576, f_bh + 0,
                                             bufA, nullptr, nullptr, 1024, 1024, rowsPad, 8);
    gemm_kernel<1><<<nblk, 256, 0, stream>>>(bufA, Wt_fh + (size_t)1 * 1048576, f_bh + 1024,
                                             bufC, nullptr, nullptr, 1024, 1024, rowsPad, 8);
    gemm_kernel<2><<<nblk, 256, 0, stream>>>(bufC, Wt_fh + (size_t)2 * 1048576, f_bh + 2048,
                                             nullptr, f_Wout, pairs_f + e0, 1024, 1024, rem, 8);
  }

  // ---- reductions
  energy_kernel<<<256, 256, 0, stream>>>(pairs_e, srcI, batch, (float*)d_out);
  force_kernel<<<(E_EDGES + 255) / 256, 256, 0, stream>>>(pairs_f, srcI, vec_hat, (float*)d_out);
}